// Round 6
// baseline (102006.482 us; speedup 1.0000x reference)
//
#include <hip/hip_runtime.h>
#include <stdint.h>

// LSTM: SEQ=512, BATCH=32, IN=HID=1024, LAYERS=4. Inputs fp32, OUTPUT FP32.
// out (float): [512*32*1024 h_seq(layer3)] ++ [4*32*1024 h_last] ++ [4*32*1024 c_last]
//
// Round-6: (1) d_out is FLOAT (reference returns fp32; the bit-identical 1.0909
// error across rounds 1-3 is only explainable as fp32-reads of our packed u16
// writes). (2) bf16x3 precision: every GEMM operand is split hi+lo bf16 and we
// compute hi*hi + hi*lo + lo*hi  (~2^-17 rel), because plain-bf16 recurrence
// accumulates ~0.1-0.4 absolute error in integrator cells over 512 steps
// (observed c = -1.046875 vs ref max 0.685) vs the 0.0214 absolute threshold.

#define SEQ    512
#define BATCH  32
#define HID    1024
#define G4     4096
#define LAYERS 4

typedef unsigned short u16;
typedef __attribute__((ext_vector_type(8))) short bf8;   // 8 bf16 (4 VGPRs) MFMA frag
typedef __attribute__((ext_vector_type(4))) float f4;

__device__ __forceinline__ u16 f2bf(float f) {           // RNE fp32->bf16
  uint32_t u = __float_as_uint(f);
  u += 0x7FFFu + ((u >> 16) & 1u);
  return (u16)(u >> 16);
}
__device__ __forceinline__ float bf2f(u16 h) {
  return __uint_as_float(((uint32_t)h) << 16);
}

// ---------------- split fp32 -> (hi, lo) bf16 ----------------
__global__ void cvt_split_kernel(const float* __restrict__ in, u16* __restrict__ hi,
                                 u16* __restrict__ lo, int n4) {
  int i = blockIdx.x * 256 + threadIdx.x;
  if (i >= n4) return;
  float4 v = reinterpret_cast<const float4*>(in)[i];
  ushort4 h, l;
  h.x = f2bf(v.x); l.x = f2bf(v.x - bf2f(h.x));
  h.y = f2bf(v.y); l.y = f2bf(v.y - bf2f(h.y));
  h.z = f2bf(v.z); l.z = f2bf(v.z - bf2f(h.z));
  h.w = f2bf(v.w); l.w = f2bf(v.w - bf2f(h.w));
  reinterpret_cast<ushort4*>(hi)[i] = h;
  reinterpret_cast<ushort4*>(lo)[i] = l;
}

__global__ void bias_comb_kernel(const float* __restrict__ a, const float* __restrict__ b,
                                 float* __restrict__ o, int n) {
  int i = blockIdx.x * 256 + threadIdx.x;
  if (i < n) o[i] = a[i] + b[i];
}

// ---------------- input projection GEMM, bf16x3 ----------------
// C[M][4096] = A[M][1024] @ W[4096][1024]^T + bias, A/W given as hi/lo bf16.
// block tile 128x128, BK=32, 4 waves (2x2 of 64x64), 16x16x32 bf16 MFMA,
// 3 MFMAs per fragment pair: ah*bh + ah*bl + al*bh.
__launch_bounds__(256)
__global__ void gemm_xproj(const u16* __restrict__ Ah, const u16* __restrict__ Al,
                           const u16* __restrict__ Bh, const u16* __restrict__ Bl,
                           const float* __restrict__ bias, float* __restrict__ C) {
  __shared__ u16 Ash[128 * 32];
  __shared__ u16 Asl[128 * 32];
  __shared__ u16 Bsh[128 * 32];
  __shared__ u16 Bsl[128 * 32];
  const int tid  = threadIdx.x;
  const int lane = tid & 63;
  const int w    = tid >> 6;
  const int wm   = (w >> 1) * 64, wn = (w & 1) * 64;
  const int m0   = blockIdx.x * 128, n0 = blockIdx.y * 128;
  const int fr   = lane & 15;            // frag row (A:m / B:n)
  const int fk   = (lane >> 4) * 8;      // frag k offset
  const f4 fz = {0.f, 0.f, 0.f, 0.f};
  f4 acc[4][4];
#pragma unroll
  for (int i = 0; i < 4; ++i)
#pragma unroll
    for (int j = 0; j < 4; ++j) acc[i][j] = fz;

  for (int kt = 0; kt < 1024; kt += 32) {
    __syncthreads();   // previous compute done before overwriting LDS
#pragma unroll
    for (int i = 0; i < 2; ++i) {
      const int e   = (i * 256 + tid) * 8;             // element index in 128x32 tile
      const int row = e >> 5, kc = e & 31;
      const int ldsbase = (i * 256 + (tid & 192)) * 8; // wave-uniform LDS base (elements)
      const size_t goffA = (size_t)(m0 + row) * 1024 + kt + kc;
      const size_t goffB = (size_t)(n0 + row) * 1024 + kt + kc;
      __builtin_amdgcn_global_load_lds(
          (const __attribute__((address_space(1))) void*)(Ah + goffA),
          (__attribute__((address_space(3))) void*)(Ash + ldsbase), 16, 0, 0);
      __builtin_amdgcn_global_load_lds(
          (const __attribute__((address_space(1))) void*)(Al + goffA),
          (__attribute__((address_space(3))) void*)(Asl + ldsbase), 16, 0, 0);
      __builtin_amdgcn_global_load_lds(
          (const __attribute__((address_space(1))) void*)(Bh + goffB),
          (__attribute__((address_space(3))) void*)(Bsh + ldsbase), 16, 0, 0);
      __builtin_amdgcn_global_load_lds(
          (const __attribute__((address_space(1))) void*)(Bl + goffB),
          (__attribute__((address_space(3))) void*)(Bsl + ldsbase), 16, 0, 0);
    }
    __syncthreads();   // compiler drains vmcnt(0) before barrier
    bf8 ah[4], al[4], bh[4], bl[4];
#pragma unroll
    for (int f = 0; f < 4; ++f) {
      ah[f] = *reinterpret_cast<const bf8*>(Ash + (wm + f * 16 + fr) * 32 + fk);
      al[f] = *reinterpret_cast<const bf8*>(Asl + (wm + f * 16 + fr) * 32 + fk);
      bh[f] = *reinterpret_cast<const bf8*>(Bsh + (wn + f * 16 + fr) * 32 + fk);
      bl[f] = *reinterpret_cast<const bf8*>(Bsl + (wn + f * 16 + fr) * 32 + fk);
    }
#pragma unroll
    for (int i = 0; i < 4; ++i)
#pragma unroll
      for (int j = 0; j < 4; ++j) {
        acc[i][j] = __builtin_amdgcn_mfma_f32_16x16x32_bf16(ah[i], bh[j], acc[i][j], 0, 0, 0);
        acc[i][j] = __builtin_amdgcn_mfma_f32_16x16x32_bf16(ah[i], bl[j], acc[i][j], 0, 0, 0);
        acc[i][j] = __builtin_amdgcn_mfma_f32_16x16x32_bf16(al[i], bh[j], acc[i][j], 0, 0, 0);
      }
  }
  // epilogue: C/D layout col=lane&15 (n), row=(lane>>4)*4+q (m)  [m89/m91]
  const int cr0 = (lane >> 4) * 4;
#pragma unroll
  for (int i = 0; i < 4; ++i)
#pragma unroll
    for (int j = 0; j < 4; ++j)
#pragma unroll
      for (int q = 0; q < 4; ++q) {
        const int rr = m0 + wm + i * 16 + cr0 + q;
        const int cc = n0 + wn + j * 16 + fr;
        C[(size_t)rr * 4096 + cc] = acc[i][j][q] + bias[cc];
      }
}

// ---------------- persistent recurrence scan (bf16x3) ----------------
// 256 blocks; block ug owns 4 hidden units (16 gate rows: {g*1024+ug*4+uu}),
// all 32 batches. W rows (hi+lo) LDS-resident. h_prev (hi+lo) is read straight
// from global (L2-resident, 128KB) into A-fragments — k-tiled layout
// h_pp[parity][hi/lo][k/8][batch][8] makes each quarter-wave load 256B
// contiguous. Per step, per wave (kh=k-half, mt=batch-half): 16 k-chunks x
// 3 MFMAs. LDS k-reduce -> fp32 gate math -> grid barrier.
#define WLD   1032                              // padded W row stride (bf16 elems)
#define HPP_Q 32768                             // u16 elems per (parity,term) plane
#define SSMEM (32 * WLD * 2 + 4096)             // Wh 33024 + Wl 33024 + red 4096 = 70144 B

__launch_bounds__(256, 1)
__global__ void lstm_scan(const float* __restrict__ gates,   // [nsteps*32][4096] fp32
                          const u16* __restrict__ Whh_hi,    // [4096][1024] bf16
                          const u16* __restrict__ Whh_lo,
                          u16* __restrict__ h_pp,            // [2][2][128][32][8] u16
                          float* __restrict__ c_glob,        // [32][1024] fp32
                          float* __restrict__ hseq_f,        // [(t*32+b)*1024+u] fp32 (d_out)
                          float* __restrict__ hs_out,        // [b*1024+u] fp32
                          float* __restrict__ cs_out,        // [b*1024+u] fp32
                          int* __restrict__ slots, int* __restrict__ go,
                          int t0, int tag0, int nsteps, int is_last) {
  extern __shared__ char smem[];
  u16*   Wh  = (u16*)smem;                         // [16][WLD]
  u16*   Wl  = (u16*)(smem + 16 * WLD * 2);        // [16][WLD]
  float* red = (float*)(smem + 32 * WLD * 2);      // [2 kh][2 mt][16 n][16 m]

  const int bid = blockIdx.x;      // = ug, 0..255
  const int ug  = bid;
  const int tid = threadIdx.x, lane = tid & 63, w = tid >> 6;

  // stage 16 W rows (hi+lo): local row n -> global gate row (n>>2)*1024 + ug*4 + (n&3)
  {
    const int n  = tid & 15;
    const int ch = tid >> 4;                       // 16 column chunks of 64
    const size_t grow = (size_t)((n >> 2) * 1024 + ug * 4 + (n & 3));
    const u16* sh = Whh_hi + grow * 1024 + ch * 64;
    const u16* sl = Whh_lo + grow * 1024 + ch * 64;
    u16* dh = Wh + n * WLD + ch * 64;
    u16* dl = Wl + n * WLD + ch * 64;
#pragma unroll
    for (int it = 0; it < 8; ++it) {
      *reinterpret_cast<bf8*>(dh + it * 8) = *reinterpret_cast<const bf8*>(sh + it * 8);
      *reinterpret_cast<bf8*>(dl + it * 8) = *reinterpret_cast<const bf8*>(sl + it * 8);
    }
  }

  float c = 0.f;
  int b = 0, uu = 0, uglob = 0;
  if (tid < 128) {
    b = tid >> 2; uu = tid & 3;                    // 32 batches x 4 units
    uglob = ug * 4 + uu;
    c = c_glob[b * 1024 + uglob];
  }
  __syncthreads();

  const int fr = lane & 15, q4 = lane >> 4;
  const int mt = w & 1, kh = w >> 1;               // wave = (k-half, batch-half)
  const int laneoff = q4 * 256 + (mt * 16 + fr) * 8;   // A-frag element offset in k-tile plane
  const int wrow = fr * WLD;                       // B-frag row base (n = fr)

  for (int s = 0; s < nsteps; ++s) {
    const int t = t0 + s;
    // phase B: matvec partials. A straight from global h_pp (no LDS stage).
    {
      const u16* hh = h_pp + (size_t)((t & 1) * 2 + 0) * HPP_Q;
      const u16* hl = h_pp + (size_t)((t & 1) * 2 + 1) * HPP_Q;
      f4 acc = {0.f, 0.f, 0.f, 0.f};
#pragma unroll
      for (int kc = 0; kc < 512; kc += 32) {
        const int koff = (kh * 512 + kc) * 32;     // tile base in elements
        bf8 avh = *reinterpret_cast<const bf8*>(hh + koff + laneoff);
        bf8 avl = *reinterpret_cast<const bf8*>(hl + koff + laneoff);
        bf8 bvh = *reinterpret_cast<const bf8*>(Wh + wrow + kh * 512 + kc + q4 * 8);
        bf8 bvl = *reinterpret_cast<const bf8*>(Wl + wrow + kh * 512 + kc + q4 * 8);
        acc = __builtin_amdgcn_mfma_f32_16x16x32_bf16(avh, bvh, acc, 0, 0, 0);
        acc = __builtin_amdgcn_mfma_f32_16x16x32_bf16(avh, bvl, acc, 0, 0, 0);
        acc = __builtin_amdgcn_mfma_f32_16x16x32_bf16(avl, bvh, acc, 0, 0, 0);
      }
      // C/D: col(lane&15)=n, row((lane>>4)*4+q)=m_local
      float* rp = red + (kh * 2 + mt) * 256 + fr * 16 + q4 * 4;
      rp[0] = acc[0]; rp[1] = acc[1]; rp[2] = acc[2]; rp[3] = acc[3];
    }
    __syncthreads();
    // phase C: gate math + state update (128 threads = 32 batches x 4 units)
    if (tid < 128) {
      const int bl = b & 15, bmt = b >> 4;
      float g[4];
#pragma unroll
      for (int gg = 0; gg < 4; ++gg) {
        const int n = gg * 4 + uu;
        float pre = red[(0 + bmt) * 256 + n * 16 + bl]      // kh=0
                  + red[(2 + bmt) * 256 + n * 16 + bl];     // kh=1
        pre += gates[(size_t)(s * 32 + b) * 4096 + gg * 1024 + uglob];
        g[gg] = pre;
      }
      const float ig = 1.f / (1.f + __expf(-g[0]));
      const float fg = 1.f / (1.f + __expf(-g[1]));
      const float gt = tanhf(g[2]);
      const float og = 1.f / (1.f + __expf(-g[3]));
      c = fg * c + ig * gt;
      const float h = og * tanhf(c);
      hseq_f[((size_t)t * 32 + b) * 1024 + uglob] = h;     // fp32 to d_out
      const u16 hh16 = f2bf(h);
      const u16 hl16 = f2bf(h - bf2f(hh16));
      const int par  = (t + 1) & 1;
      const int tidx = (uglob >> 3) * 256 + b * 8 + (uglob & 7);
      h_pp[(size_t)(par * 2 + 0) * HPP_Q + tidx] = hh16;
      h_pp[(size_t)(par * 2 + 1) * HPP_Q + tidx] = hl16;
      if (is_last && s == nsteps - 1) {
        hs_out[b * 1024 + uglob] = h;
        cs_out[b * 1024 + uglob] = c;
      }
    }
    // phase D: grid barrier (monotonic tags; slots/go zeroed once per call)
    __threadfence();
    __syncthreads();
    const int tag = tag0 + s + 1;
    if (bid == 0) {
      if (w == 0) {
        if (lane == 0)
          __hip_atomic_store(slots, tag, __ATOMIC_RELEASE, __HIP_MEMORY_SCOPE_AGENT);
        for (;;) {
          int v0 = __hip_atomic_load(slots + lane * 4 + 0, __ATOMIC_ACQUIRE, __HIP_MEMORY_SCOPE_AGENT);
          int v1 = __hip_atomic_load(slots + lane * 4 + 1, __ATOMIC_ACQUIRE, __HIP_MEMORY_SCOPE_AGENT);
          int v2 = __hip_atomic_load(slots + lane * 4 + 2, __ATOMIC_ACQUIRE, __HIP_MEMORY_SCOPE_AGENT);
          int v3 = __hip_atomic_load(slots + lane * 4 + 3, __ATOMIC_ACQUIRE, __HIP_MEMORY_SCOPE_AGENT);
          if (__all(v0 >= tag && v1 >= tag && v2 >= tag && v3 >= tag)) break;
          __builtin_amdgcn_s_sleep(2);
        }
        if (lane == 0)
          __hip_atomic_store(go, tag, __ATOMIC_RELEASE, __HIP_MEMORY_SCOPE_AGENT);
      }
    } else if (tid == 0) {
      __hip_atomic_store(slots + bid, tag, __ATOMIC_RELEASE, __HIP_MEMORY_SCOPE_AGENT);
      while (__hip_atomic_load(go, __ATOMIC_ACQUIRE, __HIP_MEMORY_SCOPE_AGENT) < tag)
        __builtin_amdgcn_s_sleep(2);
    }
    __syncthreads();
  }
  if (tid < 128) c_glob[b * 1024 + uglob] = c;
}

// ---------------- host launcher ----------------
extern "C" void kernel_launch(void* const* d_in, const int* in_sizes, int n_in,
                              void* d_out, int out_size, void* d_ws, size_t ws_size,
                              hipStream_t stream) {
  const float* x   = (const float*)d_in[0];
  const float* Wih = (const float*)d_in[1];
  const float* Whh = (const float*)d_in[2];
  const float* bih = (const float*)d_in[3];
  const float* bhh = (const float*)d_in[4];
  float* out = (float*)d_out;                         // FP32 output buffer

  float* outh = out;                                  // h_seq region = inter-layer fp32 acts
  const size_t OFF1 = (size_t)SEQ * BATCH * HID;      // 16777216
  const size_t OFF2 = OFF1 + (size_t)LAYERS * BATCH * HID;

  // workspace layout
  char* ws = (char*)d_ws;
  u16*   wih_hi = (u16*)ws;                                  // 8MB (per-layer)
  u16*   wih_lo = (u16*)(ws + (8ull  << 20));                // 8MB
  u16*   whh_hi = (u16*)(ws + (16ull << 20));                // 8MB
  u16*   whh_lo = (u16*)(ws + (24ull << 20));                // 8MB
  float* biasc  = (float*)(ws + (32ull << 20));              // 64KB (all layers)
  u16*   h_pp   = (u16*)(ws + (32ull << 20) + (64ull << 10));        // 256KB
  float* c_glob = (float*)(ws + (32ull << 20) + (320ull << 10));     // 128KB
  int*   bar    = (int*)(ws + (32ull << 20) + (448ull << 10));       // 4KB
  char*  dynws  = ws + (33ull << 20);

  // chunk T: 33MB + T*(64KB xh + 64KB xl + 512KB gates) <= ws_size
  int T = 128;
  while (T > 8 && (33ull << 20) + (size_t)T * (640ull << 10) > ws_size) T >>= 1;
  const int nchunk = SEQ / T;
  u16*   xb_hi = (u16*)dynws;                                          // T*32*1024
  u16*   xb_lo = (u16*)(dynws + (size_t)T * BATCH * HID * sizeof(u16));
  float* gates = (float*)(dynws + (size_t)2 * T * BATCH * HID * sizeof(u16));

  hipFuncSetAttribute(reinterpret_cast<const void*>(lstm_scan),
                      hipFuncAttributeMaxDynamicSharedMemorySize, SSMEM);

  hipMemsetAsync(bar, 0, 4096, stream);
  bias_comb_kernel<<<(LAYERS * G4 + 255) / 256, 256, 0, stream>>>(bih, bhh, biasc, LAYERS * G4);

  int tag0 = 0;
  for (int l = 0; l < LAYERS; ++l) {
    cvt_split_kernel<<<G4 * HID / 4 / 256, 256, 0, stream>>>(
        Wih + (size_t)l * G4 * HID, wih_hi, wih_lo, G4 * HID / 4);
    cvt_split_kernel<<<G4 * HID / 4 / 256, 256, 0, stream>>>(
        Whh + (size_t)l * G4 * HID, whh_hi, whh_lo, G4 * HID / 4);
    hipMemsetAsync(h_pp, 0, 4 * HPP_Q * sizeof(u16), stream);
    hipMemsetAsync(c_glob, 0, BATCH * HID * sizeof(float), stream);
    for (int cch = 0; cch < nchunk; ++cch) {
      const float* asrc = (l == 0) ? (x + (size_t)cch * T * BATCH * HID)
                                   : (outh + (size_t)cch * T * BATCH * HID);
      cvt_split_kernel<<<T * BATCH * HID / 4 / 256, 256, 0, stream>>>(
          asrc, xb_hi, xb_lo, T * BATCH * HID / 4);
      gemm_xproj<<<dim3(T * BATCH / 128, 32), 256, 0, stream>>>(
          xb_hi, xb_lo, wih_hi, wih_lo, biasc + l * G4, gates);
      lstm_scan<<<256, 256, SSMEM, stream>>>(
          gates, whh_hi, whh_lo, h_pp, c_glob,
          outh,
          out + OFF1 + (size_t)l * BATCH * HID,
          out + OFF2 + (size_t)l * BATCH * HID,
          bar, bar + 256,
          cch * T, tag0, T, (cch == nchunk - 1) ? 1 : 0);
      tag0 += T;
    }
  }
  (void)in_sizes; (void)n_in; (void)out_size;
}

// Round 7
// 25144.180 us; speedup vs baseline: 4.0569x; 4.0569x over previous
//
#include <hip/hip_runtime.h>
#include <stdint.h>

// LSTM: SEQ=512, BATCH=32, IN=HID=1024, LAYERS=4. Inputs fp32, OUTPUT FP32.
// out (float): [512*32*1024 h_seq(layer3)] ++ [4*32*1024 h_last] ++ [4*32*1024 c_last]
//
// Round-7: barrier detox. Round-6 passed (absmax 0.00195) but burned 46us/step:
// the spin loops used ACQUIRE atomic loads (buffer_inv per poll x 255 blocks ->
// chip-wide L2 invalidation storm; FETCH_SIZE 359MB/dispatch) plus a per-step
// __threadfence from every block. Now: RELAXED polls + ONE acquire fence per
// block per step; release-store publishes h (wbl2 once); go broadcast over 32
// cache lines (<=8 pollers/line); gates slice prefetched under phase B.

#define SEQ    512
#define BATCH  32
#define HID    1024
#define G4     4096
#define LAYERS 4

typedef unsigned short u16;
typedef __attribute__((ext_vector_type(8))) short bf8;   // 8 bf16 (4 VGPRs) MFMA frag
typedef __attribute__((ext_vector_type(4))) float f4;

__device__ __forceinline__ u16 f2bf(float f) {           // RNE fp32->bf16
  uint32_t u = __float_as_uint(f);
  u += 0x7FFFu + ((u >> 16) & 1u);
  return (u16)(u >> 16);
}
__device__ __forceinline__ float bf2f(u16 h) {
  return __uint_as_float(((uint32_t)h) << 16);
}

// ---------------- split fp32 -> (hi, lo) bf16 ----------------
__global__ void cvt_split_kernel(const float* __restrict__ in, u16* __restrict__ hi,
                                 u16* __restrict__ lo, int n4) {
  int i = blockIdx.x * 256 + threadIdx.x;
  if (i >= n4) return;
  float4 v = reinterpret_cast<const float4*>(in)[i];
  ushort4 h, l;
  h.x = f2bf(v.x); l.x = f2bf(v.x - bf2f(h.x));
  h.y = f2bf(v.y); l.y = f2bf(v.y - bf2f(h.y));
  h.z = f2bf(v.z); l.z = f2bf(v.z - bf2f(h.z));
  h.w = f2bf(v.w); l.w = f2bf(v.w - bf2f(h.w));
  reinterpret_cast<ushort4*>(hi)[i] = h;
  reinterpret_cast<ushort4*>(lo)[i] = l;
}

__global__ void bias_comb_kernel(const float* __restrict__ a, const float* __restrict__ b,
                                 float* __restrict__ o, int n) {
  int i = blockIdx.x * 256 + threadIdx.x;
  if (i < n) o[i] = a[i] + b[i];
}

// ---------------- input projection GEMM, bf16x3 ----------------
// C[M][4096] = A[M][1024] @ W[4096][1024]^T + bias, A/W given as hi/lo bf16.
// block tile 128x128, BK=32, 4 waves (2x2 of 64x64), 16x16x32 bf16 MFMA,
// 3 MFMAs per fragment pair: ah*bh + ah*bl + al*bh.
__launch_bounds__(256)
__global__ void gemm_xproj(const u16* __restrict__ Ah, const u16* __restrict__ Al,
                           const u16* __restrict__ Bh, const u16* __restrict__ Bl,
                           const float* __restrict__ bias, float* __restrict__ C) {
  __shared__ u16 Ash[128 * 32];
  __shared__ u16 Asl[128 * 32];
  __shared__ u16 Bsh[128 * 32];
  __shared__ u16 Bsl[128 * 32];
  const int tid  = threadIdx.x;
  const int lane = tid & 63;
  const int w    = tid >> 6;
  const int wm   = (w >> 1) * 64, wn = (w & 1) * 64;
  const int m0   = blockIdx.x * 128, n0 = blockIdx.y * 128;
  const int fr   = lane & 15;            // frag row (A:m / B:n)
  const int fk   = (lane >> 4) * 8;      // frag k offset
  const f4 fz = {0.f, 0.f, 0.f, 0.f};
  f4 acc[4][4];
#pragma unroll
  for (int i = 0; i < 4; ++i)
#pragma unroll
    for (int j = 0; j < 4; ++j) acc[i][j] = fz;

  for (int kt = 0; kt < 1024; kt += 32) {
    __syncthreads();   // previous compute done before overwriting LDS
#pragma unroll
    for (int i = 0; i < 2; ++i) {
      const int e   = (i * 256 + tid) * 8;             // element index in 128x32 tile
      const int row = e >> 5, kc = e & 31;
      const int ldsbase = (i * 256 + (tid & 192)) * 8; // wave-uniform LDS base (elements)
      const size_t goffA = (size_t)(m0 + row) * 1024 + kt + kc;
      const size_t goffB = (size_t)(n0 + row) * 1024 + kt + kc;
      __builtin_amdgcn_global_load_lds(
          (const __attribute__((address_space(1))) void*)(Ah + goffA),
          (__attribute__((address_space(3))) void*)(Ash + ldsbase), 16, 0, 0);
      __builtin_amdgcn_global_load_lds(
          (const __attribute__((address_space(1))) void*)(Al + goffA),
          (__attribute__((address_space(3))) void*)(Asl + ldsbase), 16, 0, 0);
      __builtin_amdgcn_global_load_lds(
          (const __attribute__((address_space(1))) void*)(Bh + goffB),
          (__attribute__((address_space(3))) void*)(Bsh + ldsbase), 16, 0, 0);
      __builtin_amdgcn_global_load_lds(
          (const __attribute__((address_space(1))) void*)(Bl + goffB),
          (__attribute__((address_space(3))) void*)(Bsl + ldsbase), 16, 0, 0);
    }
    __syncthreads();   // compiler drains vmcnt(0) before barrier
    bf8 ah[4], al[4], bh[4], bl[4];
#pragma unroll
    for (int f = 0; f < 4; ++f) {
      ah[f] = *reinterpret_cast<const bf8*>(Ash + (wm + f * 16 + fr) * 32 + fk);
      al[f] = *reinterpret_cast<const bf8*>(Asl + (wm + f * 16 + fr) * 32 + fk);
      bh[f] = *reinterpret_cast<const bf8*>(Bsh + (wn + f * 16 + fr) * 32 + fk);
      bl[f] = *reinterpret_cast<const bf8*>(Bsl + (wn + f * 16 + fr) * 32 + fk);
    }
#pragma unroll
    for (int i = 0; i < 4; ++i)
#pragma unroll
      for (int j = 0; j < 4; ++j) {
        acc[i][j] = __builtin_amdgcn_mfma_f32_16x16x32_bf16(ah[i], bh[j], acc[i][j], 0, 0, 0);
        acc[i][j] = __builtin_amdgcn_mfma_f32_16x16x32_bf16(ah[i], bl[j], acc[i][j], 0, 0, 0);
        acc[i][j] = __builtin_amdgcn_mfma_f32_16x16x32_bf16(al[i], bh[j], acc[i][j], 0, 0, 0);
      }
  }
  // epilogue: C/D layout col=lane&15 (n), row=(lane>>4)*4+q (m)  [m89/m91]
  const int cr0 = (lane >> 4) * 4;
#pragma unroll
  for (int i = 0; i < 4; ++i)
#pragma unroll
    for (int j = 0; j < 4; ++j)
#pragma unroll
      for (int q = 0; q < 4; ++q) {
        const int rr = m0 + wm + i * 16 + cr0 + q;
        const int cc = n0 + wn + j * 16 + fr;
        C[(size_t)rr * 4096 + cc] = acc[i][j][q] + bias[cc];
      }
}

// ---------------- persistent recurrence scan (bf16x3) ----------------
// 256 blocks; block ug owns 4 hidden units (16 gate rows: {g*1024+ug*4+uu}),
// all 32 batches. W rows (hi+lo) LDS-resident. h_prev (hi+lo) read straight
// from global into A-fragments (k-tiled layout h_pp[par][term][k/8][b][8]).
// Per step: prefetch gates slice -> MFMA partials -> LDS reduce -> gate math
// -> grid barrier (relaxed polls, one acquire fence per block per step).
#define WLD   1032                              // padded W row stride (bf16 elems)
#define HPP_Q 32768                             // u16 elems per (parity,term) plane
#define SSMEM (32 * WLD * 2 + 4096)             // Wh 33024 + Wl 33024 + red 4096 = 70144 B

__launch_bounds__(256, 1)
__global__ void lstm_scan(const float* __restrict__ gates,   // [nsteps*32][4096] fp32
                          const u16* __restrict__ Whh_hi,    // [4096][1024] bf16
                          const u16* __restrict__ Whh_lo,
                          u16* __restrict__ h_pp,            // [2][2][128][32][8] u16
                          float* __restrict__ c_glob,        // [32][1024] fp32
                          float* __restrict__ hseq_f,        // [(t*32+b)*1024+u] fp32 (d_out)
                          float* __restrict__ hs_out,        // [b*1024+u] fp32
                          float* __restrict__ cs_out,        // [b*1024+u] fp32
                          int* __restrict__ slots,           // [256] one per block
                          int* __restrict__ go_rep,          // [32*16] go copies, 1/line
                          int t0, int tag0, int nsteps, int is_last) {
  extern __shared__ char smem[];
  u16*   Wh  = (u16*)smem;                         // [16][WLD]
  u16*   Wl  = (u16*)(smem + 16 * WLD * 2);        // [16][WLD]
  float* red = (float*)(smem + 32 * WLD * 2);      // [2 kh][2 mt][16 n][16 m]

  const int bid = blockIdx.x;      // = ug, 0..255
  const int ug  = bid;
  const int tid = threadIdx.x, lane = tid & 63, w = tid >> 6;

  // stage 16 W rows (hi+lo): local row n -> global gate row (n>>2)*1024 + ug*4 + (n&3)
  {
    const int n  = tid & 15;
    const int ch = tid >> 4;                       // 16 column chunks of 64
    const size_t grow = (size_t)((n >> 2) * 1024 + ug * 4 + (n & 3));
    const u16* sh = Whh_hi + grow * 1024 + ch * 64;
    const u16* sl = Whh_lo + grow * 1024 + ch * 64;
    u16* dh = Wh + n * WLD + ch * 64;
    u16* dl = Wl + n * WLD + ch * 64;
#pragma unroll
    for (int it = 0; it < 8; ++it) {
      *reinterpret_cast<bf8*>(dh + it * 8) = *reinterpret_cast<const bf8*>(sh + it * 8);
      *reinterpret_cast<bf8*>(dl + it * 8) = *reinterpret_cast<const bf8*>(sl + it * 8);
    }
  }

  float c = 0.f;
  int b = 0, uu = 0, uglob = 0;
  if (tid < 128) {
    b = tid >> 2; uu = tid & 3;                    // 32 batches x 4 units
    uglob = ug * 4 + uu;
    c = c_glob[b * 1024 + uglob];
  }
  __syncthreads();

  const int fr = lane & 15, q4 = lane >> 4;
  const int mt = w & 1, kh = w >> 1;               // wave = (k-half, batch-half)
  const int laneoff = q4 * 256 + (mt * 16 + fr) * 8;   // A-frag element offset in k-tile plane
  const int wrow = fr * WLD;                       // B-frag row base (n = fr)

  for (int s = 0; s < nsteps; ++s) {
    const int t = t0 + s;
    // gates prefetch: issue early so HBM latency hides under phase B
    float gp0 = 0.f, gp1 = 0.f, gp2 = 0.f, gp3 = 0.f;
    if (tid < 128) {
      const float* gr = gates + (size_t)(s * 32 + b) * 4096 + uglob;
      gp0 = gr[0]; gp1 = gr[1024]; gp2 = gr[2048]; gp3 = gr[3072];
    }
    // phase B: matvec partials. A straight from global h_pp (no LDS stage).
    {
      const u16* hh = h_pp + (size_t)((t & 1) * 2 + 0) * HPP_Q;
      const u16* hl = h_pp + (size_t)((t & 1) * 2 + 1) * HPP_Q;
      f4 acc = {0.f, 0.f, 0.f, 0.f};
#pragma unroll
      for (int kc = 0; kc < 512; kc += 32) {
        const int koff = (kh * 512 + kc) * 32;     // tile base in elements
        bf8 avh = *reinterpret_cast<const bf8*>(hh + koff + laneoff);
        bf8 avl = *reinterpret_cast<const bf8*>(hl + koff + laneoff);
        bf8 bvh = *reinterpret_cast<const bf8*>(Wh + wrow + kh * 512 + kc + q4 * 8);
        bf8 bvl = *reinterpret_cast<const bf8*>(Wl + wrow + kh * 512 + kc + q4 * 8);
        acc = __builtin_amdgcn_mfma_f32_16x16x32_bf16(avh, bvh, acc, 0, 0, 0);
        acc = __builtin_amdgcn_mfma_f32_16x16x32_bf16(avh, bvl, acc, 0, 0, 0);
        acc = __builtin_amdgcn_mfma_f32_16x16x32_bf16(avl, bvh, acc, 0, 0, 0);
      }
      // C/D: col(lane&15)=n, row((lane>>4)*4+q)=m_local
      float* rp = red + (kh * 2 + mt) * 256 + fr * 16 + q4 * 4;
      rp[0] = acc[0]; rp[1] = acc[1]; rp[2] = acc[2]; rp[3] = acc[3];
    }
    __syncthreads();
    // phase C: gate math + state update (128 threads = 32 batches x 4 units)
    if (tid < 128) {
      const int bl = b & 15, bmt = b >> 4;
      float g0, g1, g2, g3;
      {
        const int n0i = 0 * 4 + uu, n1i = 1 * 4 + uu, n2i = 2 * 4 + uu, n3i = 3 * 4 + uu;
        g0 = red[(0 + bmt) * 256 + n0i * 16 + bl] + red[(2 + bmt) * 256 + n0i * 16 + bl] + gp0;
        g1 = red[(0 + bmt) * 256 + n1i * 16 + bl] + red[(2 + bmt) * 256 + n1i * 16 + bl] + gp1;
        g2 = red[(0 + bmt) * 256 + n2i * 16 + bl] + red[(2 + bmt) * 256 + n2i * 16 + bl] + gp2;
        g3 = red[(0 + bmt) * 256 + n3i * 16 + bl] + red[(2 + bmt) * 256 + n3i * 16 + bl] + gp3;
      }
      const float ig = 1.f / (1.f + __expf(-g0));
      const float fg = 1.f / (1.f + __expf(-g1));
      const float gt = tanhf(g2);
      const float og = 1.f / (1.f + __expf(-g3));
      c = fg * c + ig * gt;
      const float h = og * tanhf(c);
      hseq_f[((size_t)t * 32 + b) * 1024 + uglob] = h;     // fp32 to d_out
      const u16 hh16 = f2bf(h);
      const u16 hl16 = f2bf(h - bf2f(hh16));
      const int par  = (t + 1) & 1;
      const int tidx = (uglob >> 3) * 256 + b * 8 + (uglob & 7);
      h_pp[(size_t)(par * 2 + 0) * HPP_Q + tidx] = hh16;
      h_pp[(size_t)(par * 2 + 1) * HPP_Q + tidx] = hl16;
      if (is_last && s == nsteps - 1) {
        hs_out[b * 1024 + uglob] = h;
        cs_out[b * 1024 + uglob] = c;
      }
    }
    // phase D: grid barrier.
    //  - __syncthreads drains this block's stores into L2 (vmcnt0 before s_barrier)
    //  - tid0 RELEASE store publishes them (waitcnt + wbl2 once per block/step)
    //  - spins use RELAXED loads (no buffer_inv per poll!), then ONE acquire
    //    fence per block/step makes next step's h reads fetch fresh data.
    __syncthreads();
    const int tag = tag0 + s + 1;
    if (tid == 0)
      __hip_atomic_store(slots + bid, tag, __ATOMIC_RELEASE, __HIP_MEMORY_SCOPE_AGENT);
    if (bid == 0) {
      if (w == 0) {
        for (;;) {
          int v0 = __hip_atomic_load(slots + lane * 4 + 0, __ATOMIC_RELAXED, __HIP_MEMORY_SCOPE_AGENT);
          int v1 = __hip_atomic_load(slots + lane * 4 + 1, __ATOMIC_RELAXED, __HIP_MEMORY_SCOPE_AGENT);
          int v2 = __hip_atomic_load(slots + lane * 4 + 2, __ATOMIC_RELAXED, __HIP_MEMORY_SCOPE_AGENT);
          int v3 = __hip_atomic_load(slots + lane * 4 + 3, __ATOMIC_RELAXED, __HIP_MEMORY_SCOPE_AGENT);
          if (__all(v0 >= tag && v1 >= tag && v2 >= tag && v3 >= tag)) break;
          __builtin_amdgcn_s_sleep(1);
        }
        // orders slot reads before go stores; inv for this block's next h reads
        __builtin_amdgcn_fence(__ATOMIC_ACQ_REL, "agent");
        if (lane < 32)
          __hip_atomic_store(go_rep + lane * 16, tag, __ATOMIC_RELAXED, __HIP_MEMORY_SCOPE_AGENT);
      }
    } else if (tid == 0) {
      while (__hip_atomic_load(go_rep + (bid & 31) * 16, __ATOMIC_RELAXED, __HIP_MEMORY_SCOPE_AGENT) < tag)
        __builtin_amdgcn_s_sleep(4);
      __builtin_amdgcn_fence(__ATOMIC_ACQUIRE, "agent");
    }
    __syncthreads();
  }
  if (tid < 128) c_glob[b * 1024 + uglob] = c;
}

// ---------------- host launcher ----------------
extern "C" void kernel_launch(void* const* d_in, const int* in_sizes, int n_in,
                              void* d_out, int out_size, void* d_ws, size_t ws_size,
                              hipStream_t stream) {
  const float* x   = (const float*)d_in[0];
  const float* Wih = (const float*)d_in[1];
  const float* Whh = (const float*)d_in[2];
  const float* bih = (const float*)d_in[3];
  const float* bhh = (const float*)d_in[4];
  float* out = (float*)d_out;                         // FP32 output buffer

  float* outh = out;                                  // h_seq region = inter-layer fp32 acts
  const size_t OFF1 = (size_t)SEQ * BATCH * HID;      // 16777216
  const size_t OFF2 = OFF1 + (size_t)LAYERS * BATCH * HID;

  // workspace layout
  char* ws = (char*)d_ws;
  u16*   wih_hi = (u16*)ws;                                  // 8MB (per-layer)
  u16*   wih_lo = (u16*)(ws + (8ull  << 20));                // 8MB
  u16*   whh_hi = (u16*)(ws + (16ull << 20));                // 8MB
  u16*   whh_lo = (u16*)(ws + (24ull << 20));                // 8MB
  float* biasc  = (float*)(ws + (32ull << 20));              // 64KB (all layers)
  u16*   h_pp   = (u16*)(ws + (32ull << 20) + (64ull << 10));        // 256KB
  float* c_glob = (float*)(ws + (32ull << 20) + (320ull << 10));     // 128KB
  int*   bar    = (int*)(ws + (32ull << 20) + (448ull << 10));       // 4KB: slots[256] ++ go_rep[512]
  char*  dynws  = ws + (33ull << 20);

  // chunk T: 33MB + T*(64KB xh + 64KB xl + 512KB gates) <= ws_size
  int T = 128;
  while (T > 8 && (33ull << 20) + (size_t)T * (640ull << 10) > ws_size) T >>= 1;
  const int nchunk = SEQ / T;
  u16*   xb_hi = (u16*)dynws;                                          // T*32*1024
  u16*   xb_lo = (u16*)(dynws + (size_t)T * BATCH * HID * sizeof(u16));
  float* gates = (float*)(dynws + (size_t)2 * T * BATCH * HID * sizeof(u16));

  hipFuncSetAttribute(reinterpret_cast<const void*>(lstm_scan),
                      hipFuncAttributeMaxDynamicSharedMemorySize, SSMEM);

  hipMemsetAsync(bar, 0, 4096, stream);
  bias_comb_kernel<<<(LAYERS * G4 + 255) / 256, 256, 0, stream>>>(bih, bhh, biasc, LAYERS * G4);

  int tag0 = 0;
  for (int l = 0; l < LAYERS; ++l) {
    cvt_split_kernel<<<G4 * HID / 4 / 256, 256, 0, stream>>>(
        Wih + (size_t)l * G4 * HID, wih_hi, wih_lo, G4 * HID / 4);
    cvt_split_kernel<<<G4 * HID / 4 / 256, 256, 0, stream>>>(
        Whh + (size_t)l * G4 * HID, whh_hi, whh_lo, G4 * HID / 4);
    hipMemsetAsync(h_pp, 0, 4 * HPP_Q * sizeof(u16), stream);
    hipMemsetAsync(c_glob, 0, BATCH * HID * sizeof(float), stream);
    for (int cch = 0; cch < nchunk; ++cch) {
      const float* asrc = (l == 0) ? (x + (size_t)cch * T * BATCH * HID)
                                   : (outh + (size_t)cch * T * BATCH * HID);
      cvt_split_kernel<<<T * BATCH * HID / 4 / 256, 256, 0, stream>>>(
          asrc, xb_hi, xb_lo, T * BATCH * HID / 4);
      gemm_xproj<<<dim3(T * BATCH / 128, 32), 256, 0, stream>>>(
          xb_hi, xb_lo, wih_hi, wih_lo, biasc + l * G4, gates);
      lstm_scan<<<256, 256, SSMEM, stream>>>(
          gates, whh_hi, whh_lo, h_pp, c_glob,
          outh,
          out + OFF1 + (size_t)l * BATCH * HID,
          out + OFF2 + (size_t)l * BATCH * HID,
          bar, bar + 256,
          cch * T, tag0, T, (cch == nchunk - 1) ? 1 : 0);
      tag0 += T;
    }
  }
  (void)in_sizes; (void)n_in; (void)out_size;
}

// Round 8
// 14746.880 us; speedup vs baseline: 6.9172x; 1.7051x over previous
//
#include <hip/hip_runtime.h>
#include <stdint.h>

// LSTM: SEQ=512, BATCH=32, IN=HID=1024, LAYERS=4. Inputs fp32, OUTPUT FP32.
// out (float): [512*32*1024 h_seq(layer3)] ++ [4*32*1024 h_last] ++ [4*32*1024 c_last]
//
// Round-8: latency surgery on the scan.
//  - h ping-pong traffic goes through RELAXED agent atomics (sc1 -> L3 direct):
//    no acquire fences at all => no per-block L2-invalidation storm (round-7's
//    hidden cost: 32 blocks/XCD invalidating at staggered times killed each
//    other's h lines mid-phase-B; FETCH 337MB >> gates' 64MB).
//  - 128 blocks x 32 W-rows (LDS 145KB): halves chip-wide h read volume
//    (32MB -> 16MB/step) and halves barrier participants.
//  - waves = 4 K-quarters, each M=32 x N=32 (2x2 subtiles): zero intra-block
//    operand duplication. hseq/h stores packed as u64/u32 atomics.

#define SEQ    512
#define BATCH  32
#define HID    1024
#define G4     4096
#define LAYERS 4

typedef unsigned short u16;
typedef unsigned int u32;
typedef unsigned long long u64;
typedef __attribute__((ext_vector_type(8))) short bf8;   // 8 bf16 (4 VGPRs) MFMA frag
typedef __attribute__((ext_vector_type(4))) float f4;

__device__ __forceinline__ u16 f2bf(float f) {           // RNE fp32->bf16
  uint32_t u = __float_as_uint(f);
  u += 0x7FFFu + ((u >> 16) & 1u);
  return (u16)(u >> 16);
}
__device__ __forceinline__ float bf2f(u16 h) {
  return __uint_as_float(((uint32_t)h) << 16);
}
__device__ __forceinline__ float sigf(float x) { return 1.f / (1.f + __expf(-x)); }

// 16B load as two relaxed agent-scope 8B atomics (sc1: bypass L2, read L3)
__device__ __forceinline__ bf8 ld_bf8_sc(const u16* p) {
  union { u64 q[2]; bf8 v; } u;
  const u64* qp = (const u64*)p;
  u.q[0] = __hip_atomic_load(qp,     __ATOMIC_RELAXED, __HIP_MEMORY_SCOPE_AGENT);
  u.q[1] = __hip_atomic_load(qp + 1, __ATOMIC_RELAXED, __HIP_MEMORY_SCOPE_AGENT);
  return u.v;
}

// ---------------- split fp32 -> (hi, lo) bf16 ----------------
__global__ void cvt_split_kernel(const float* __restrict__ in, u16* __restrict__ hi,
                                 u16* __restrict__ lo, int n4) {
  int i = blockIdx.x * 256 + threadIdx.x;
  if (i >= n4) return;
  float4 v = reinterpret_cast<const float4*>(in)[i];
  ushort4 h, l;
  h.x = f2bf(v.x); l.x = f2bf(v.x - bf2f(h.x));
  h.y = f2bf(v.y); l.y = f2bf(v.y - bf2f(h.y));
  h.z = f2bf(v.z); l.z = f2bf(v.z - bf2f(h.z));
  h.w = f2bf(v.w); l.w = f2bf(v.w - bf2f(h.w));
  reinterpret_cast<ushort4*>(hi)[i] = h;
  reinterpret_cast<ushort4*>(lo)[i] = l;
}

__global__ void bias_comb_kernel(const float* __restrict__ a, const float* __restrict__ b,
                                 float* __restrict__ o, int n) {
  int i = blockIdx.x * 256 + threadIdx.x;
  if (i < n) o[i] = a[i] + b[i];
}

// ---------------- input projection GEMM, bf16x3 (unchanged, passing) ----------------
__launch_bounds__(256)
__global__ void gemm_xproj(const u16* __restrict__ Ah, const u16* __restrict__ Al,
                           const u16* __restrict__ Bh, const u16* __restrict__ Bl,
                           const float* __restrict__ bias, float* __restrict__ C) {
  __shared__ u16 Ash[128 * 32];
  __shared__ u16 Asl[128 * 32];
  __shared__ u16 Bsh[128 * 32];
  __shared__ u16 Bsl[128 * 32];
  const int tid  = threadIdx.x;
  const int lane = tid & 63;
  const int w    = tid >> 6;
  const int wm   = (w >> 1) * 64, wn = (w & 1) * 64;
  const int m0   = blockIdx.x * 128, n0 = blockIdx.y * 128;
  const int fr   = lane & 15;
  const int fk   = (lane >> 4) * 8;
  const f4 fz = {0.f, 0.f, 0.f, 0.f};
  f4 acc[4][4];
#pragma unroll
  for (int i = 0; i < 4; ++i)
#pragma unroll
    for (int j = 0; j < 4; ++j) acc[i][j] = fz;

  for (int kt = 0; kt < 1024; kt += 32) {
    __syncthreads();
#pragma unroll
    for (int i = 0; i < 2; ++i) {
      const int e   = (i * 256 + tid) * 8;
      const int row = e >> 5, kc = e & 31;
      const int ldsbase = (i * 256 + (tid & 192)) * 8;
      const size_t goffA = (size_t)(m0 + row) * 1024 + kt + kc;
      const size_t goffB = (size_t)(n0 + row) * 1024 + kt + kc;
      __builtin_amdgcn_global_load_lds(
          (const __attribute__((address_space(1))) void*)(Ah + goffA),
          (__attribute__((address_space(3))) void*)(Ash + ldsbase), 16, 0, 0);
      __builtin_amdgcn_global_load_lds(
          (const __attribute__((address_space(1))) void*)(Al + goffA),
          (__attribute__((address_space(3))) void*)(Asl + ldsbase), 16, 0, 0);
      __builtin_amdgcn_global_load_lds(
          (const __attribute__((address_space(1))) void*)(Bh + goffB),
          (__attribute__((address_space(3))) void*)(Bsh + ldsbase), 16, 0, 0);
      __builtin_amdgcn_global_load_lds(
          (const __attribute__((address_space(1))) void*)(Bl + goffB),
          (__attribute__((address_space(3))) void*)(Bsl + ldsbase), 16, 0, 0);
    }
    __syncthreads();
    bf8 ah[4], al[4], bh[4], bl[4];
#pragma unroll
    for (int f = 0; f < 4; ++f) {
      ah[f] = *reinterpret_cast<const bf8*>(Ash + (wm + f * 16 + fr) * 32 + fk);
      al[f] = *reinterpret_cast<const bf8*>(Asl + (wm + f * 16 + fr) * 32 + fk);
      bh[f] = *reinterpret_cast<const bf8*>(Bsh + (wn + f * 16 + fr) * 32 + fk);
      bl[f] = *reinterpret_cast<const bf8*>(Bsl + (wn + f * 16 + fr) * 32 + fk);
    }
#pragma unroll
    for (int i = 0; i < 4; ++i)
#pragma unroll
      for (int j = 0; j < 4; ++j) {
        acc[i][j] = __builtin_amdgcn_mfma_f32_16x16x32_bf16(ah[i], bh[j], acc[i][j], 0, 0, 0);
        acc[i][j] = __builtin_amdgcn_mfma_f32_16x16x32_bf16(ah[i], bl[j], acc[i][j], 0, 0, 0);
        acc[i][j] = __builtin_amdgcn_mfma_f32_16x16x32_bf16(al[i], bh[j], acc[i][j], 0, 0, 0);
      }
  }
  const int cr0 = (lane >> 4) * 4;
#pragma unroll
  for (int i = 0; i < 4; ++i)
#pragma unroll
    for (int j = 0; j < 4; ++j)
#pragma unroll
      for (int q = 0; q < 4; ++q) {
        const int rr = m0 + wm + i * 16 + cr0 + q;
        const int cc = n0 + wn + j * 16 + fr;
        C[(size_t)rr * 4096 + cc] = acc[i][j][q] + bias[cc];
      }
}

// ---------------- persistent recurrence scan (bf16x3, 128 blocks) ----------------
// block ug owns 8 hidden units (32 gate rows: g*1024 + ug*8 + uu, uu in [0,8)).
// W rows hi+lo LDS-resident ([32][WLD] x2 = 129KB). h ping-pong in global,
// layout [par][term][ktile=128][b=32][8] u16; ALL h accesses are relaxed agent
// atomics (sc1 -> L3) so no fences / no L2 invalidation anywhere in the loop.
// Waves = 4 K-quarters; per wave M=32 (2 mt) x N=32 (2 nt), 96 MFMA/step.
#define WLD   1032                              // padded W row stride (bf16 elems)
#define HPP_Q 32768                             // u16 elems per (parity,term) plane
#define WBYTES (32 * WLD * 2)                   // 66048
#define SSMEM (2 * WBYTES + 16384)              // Wh + Wl + red = 148480 B

__launch_bounds__(256, 1)
__global__ void lstm_scan(const float* __restrict__ gates,   // [nsteps*32][4096] fp32
                          const u16* __restrict__ Whh_hi,    // [4096][1024] bf16
                          const u16* __restrict__ Whh_lo,
                          u16* __restrict__ h_pp,            // [2][2][128][32][8] u16
                          float* __restrict__ c_glob,        // [32][1024] fp32
                          float* __restrict__ hseq_f,        // [(t*32+b)*1024+u] fp32 (d_out)
                          float* __restrict__ hs_out,        // [b*1024+u] fp32
                          float* __restrict__ cs_out,        // [b*1024+u] fp32
                          int* __restrict__ slots,           // [128]
                          int* __restrict__ go_rep,          // [32*16] go copies, 1/line
                          int t0, int tag0, int nsteps, int is_last) {
  extern __shared__ char smem[];
  u16*   Wh  = (u16*)smem;                       // [32][WLD]
  u16*   Wl  = (u16*)(smem + WBYTES);            // [32][WLD]
  float* red = (float*)(smem + 2 * WBYTES);      // [4 khq][2 mt][32 n][16 m]

  const int bid = blockIdx.x;      // = ug, 0..127
  const int ug  = bid;
  const int tid = threadIdx.x, lane = tid & 63, w = tid >> 6;

  // stage 32 W rows (hi+lo): local row n -> global gate row (n>>3)*1024 + ug*8 + (n&7)
  {
    const int n  = tid & 31;
    const int ch = tid >> 5;                     // 8 column chunks of 128
    const size_t grow = (size_t)((n >> 3) * 1024 + ug * 8 + (n & 7));
    const u16* sh = Whh_hi + grow * 1024 + ch * 128;
    const u16* sl = Whh_lo + grow * 1024 + ch * 128;
    u16* dh = Wh + n * WLD + ch * 128;
    u16* dl = Wl + n * WLD + ch * 128;
#pragma unroll
    for (int it = 0; it < 16; ++it) {
      *reinterpret_cast<bf8*>(dh + it * 8) = *reinterpret_cast<const bf8*>(sh + it * 8);
      *reinterpret_cast<bf8*>(dl + it * 8) = *reinterpret_cast<const bf8*>(sl + it * 8);
    }
  }

  float c0 = 0.f, c1 = 0.f;
  int b = 0, up = 0, u0 = 0;
  if (tid < 128) {
    b = tid >> 2; up = tid & 3;                  // 32 batches x 4 unit-pairs
    u0 = ug * 8 + up * 2;                        // global unit (even)
    c0 = c_glob[b * 1024 + u0];
    c1 = c_glob[b * 1024 + u0 + 1];
  }
  __syncthreads();

  const int fr = lane & 15, q4 = lane >> 4;
  const int khq = w;                             // K-quarter 0..3
  const int aeo0 = fr * 8;                       // A elem offset, mt=0
  const int aeo1 = (16 + fr) * 8;                // mt=1
  const int brow0 = fr * WLD;                    // B row base, nt=0
  const int brow1 = (16 + fr) * WLD;             // nt=1
  const int bcol0 = khq * 256 + q4 * 8;          // B col base (+kc8*8)

  const f4 fz = {0.f, 0.f, 0.f, 0.f};

  for (int s = 0; s < nsteps; ++s) {
    const int t = t0 + s;
    // gates prefetch (plain cached loads; L2 never invalidated now)
    float2 gp0, gp1, gp2, gp3;
    if (tid < 128) {
      const float* gr = gates + (size_t)(s * 32 + b) * 4096 + u0;
      gp0 = *(const float2*)(gr);
      gp1 = *(const float2*)(gr + 1024);
      gp2 = *(const float2*)(gr + 2048);
      gp3 = *(const float2*)(gr + 3072);
    }
    // phase B: matvec partials; h via sc1 atomics (L3-direct, race-free by barrier)
    {
      const u16* hh = h_pp + (size_t)((t & 1) * 2 + 0) * HPP_Q;
      const u16* hl = h_pp + (size_t)((t & 1) * 2 + 1) * HPP_Q;
      f4 a00 = fz, a01 = fz, a10 = fz, a11 = fz;   // [mt][nt]
#pragma unroll
      for (int kc8 = 0; kc8 < 32; kc8 += 4) {
        const int ab = (khq * 32 + kc8 + q4) * 256;
        bf8 avh0 = ld_bf8_sc(hh + ab + aeo0);
        bf8 avl0 = ld_bf8_sc(hl + ab + aeo0);
        bf8 avh1 = ld_bf8_sc(hh + ab + aeo1);
        bf8 avl1 = ld_bf8_sc(hl + ab + aeo1);
        const int bc = bcol0 + kc8 * 8;
        bf8 bvh0 = *reinterpret_cast<const bf8*>(Wh + brow0 + bc);
        bf8 bvl0 = *reinterpret_cast<const bf8*>(Wl + brow0 + bc);
        bf8 bvh1 = *reinterpret_cast<const bf8*>(Wh + brow1 + bc);
        bf8 bvl1 = *reinterpret_cast<const bf8*>(Wl + brow1 + bc);
        a00 = __builtin_amdgcn_mfma_f32_16x16x32_bf16(avh0, bvh0, a00, 0, 0, 0);
        a00 = __builtin_amdgcn_mfma_f32_16x16x32_bf16(avh0, bvl0, a00, 0, 0, 0);
        a00 = __builtin_amdgcn_mfma_f32_16x16x32_bf16(avl0, bvh0, a00, 0, 0, 0);
        a01 = __builtin_amdgcn_mfma_f32_16x16x32_bf16(avh0, bvh1, a01, 0, 0, 0);
        a01 = __builtin_amdgcn_mfma_f32_16x16x32_bf16(avh0, bvl1, a01, 0, 0, 0);
        a01 = __builtin_amdgcn_mfma_f32_16x16x32_bf16(avl0, bvh1, a01, 0, 0, 0);
        a10 = __builtin_amdgcn_mfma_f32_16x16x32_bf16(avh1, bvh0, a10, 0, 0, 0);
        a10 = __builtin_amdgcn_mfma_f32_16x16x32_bf16(avh1, bvl0, a10, 0, 0, 0);
        a10 = __builtin_amdgcn_mfma_f32_16x16x32_bf16(avl1, bvh0, a10, 0, 0, 0);
        a11 = __builtin_amdgcn_mfma_f32_16x16x32_bf16(avh1, bvh1, a11, 0, 0, 0);
        a11 = __builtin_amdgcn_mfma_f32_16x16x32_bf16(avh1, bvl1, a11, 0, 0, 0);
        a11 = __builtin_amdgcn_mfma_f32_16x16x32_bf16(avl1, bvh1, a11, 0, 0, 0);
      }
      // red[(khq*2+mt)*512 + (nt*16+fr)*16 + q4*4 + q]; C/D: col(lane&15)=n, row=(lane>>4)*4+q (m)
      float* r00 = red + (khq * 2 + 0) * 512 + fr * 16 + q4 * 4;
      float* r01 = r00 + 256;
      float* r10 = red + (khq * 2 + 1) * 512 + fr * 16 + q4 * 4;
      float* r11 = r10 + 256;
#pragma unroll
      for (int q = 0; q < 4; ++q) {
        r00[q] = a00[q]; r01[q] = a01[q]; r10[q] = a10[q]; r11[q] = a11[q];
      }
    }
    __syncthreads();
    // phase C: 128 threads = 32 batches x 4 unit-pairs; 2 cell updates each
    if (tid < 128) {
      const int bl = b & 15, bmt = b >> 4;
      float g00, g01, g02, g03, g10, g11, g12, g13;
      {
        const int nb0 = (up * 2) * 16 + bl;          // n = gg*8 + up*2 (+j)
        float s0, s1, s2, s3;
#pragma unroll
        for (int j = 0; j < 2; ++j) {
          const int nb = nb0 + j * 16;
          s0 = s1 = s2 = s3 = 0.f;
#pragma unroll
          for (int kq = 0; kq < 4; ++kq) {
            const float* rb = red + (kq * 2 + bmt) * 512 + nb;
            s0 += rb[0 * 128];       // gg*8*16 = gg*128
            s1 += rb[1 * 128];
            s2 += rb[2 * 128];
            s3 += rb[3 * 128];
          }
          if (j == 0) { g00 = s0 + gp0.x; g01 = s1 + gp1.x; g02 = s2 + gp2.x; g03 = s3 + gp3.x; }
          else        { g10 = s0 + gp0.y; g11 = s1 + gp1.y; g12 = s2 + gp2.y; g13 = s3 + gp3.y; }
        }
      }
      const float i0 = sigf(g00), f0 = sigf(g01), z0 = tanhf(g02), o0 = sigf(g03);
      c0 = f0 * c0 + i0 * z0;
      const float h0 = o0 * tanhf(c0);
      const float i1 = sigf(g10), f1 = sigf(g11), z1 = tanhf(g12), o1 = sigf(g13);
      c1 = f1 * c1 + i1 * z1;
      const float h1 = o1 * tanhf(c1);
      // hseq (fp32 pair, sc1 so no L2 dirty lines to flush at the release)
      const u64 hv = ((u64)__float_as_uint(h1) << 32) | (u64)__float_as_uint(h0);
      __hip_atomic_store((u64*)(hseq_f + ((size_t)t * 32 + b) * 1024 + u0), hv,
                         __ATOMIC_RELAXED, __HIP_MEMORY_SCOPE_AGENT);
      // h ping-pong (hi/lo planes, packed u32 pairs, sc1)
      const u16 h0h = f2bf(h0), h0l = f2bf(h0 - bf2f(h0h));
      const u16 h1h = f2bf(h1), h1l = f2bf(h1 - bf2f(h1h));
      const int par2 = ((t + 1) & 1) * 2;
      const int tix  = ug * 256 + b * 8 + up * 2;       // u16 idx in plane
      __hip_atomic_store((u32*)(h_pp + (size_t)par2 * HPP_Q + tix),
                         (u32)h0h | ((u32)h1h << 16),
                         __ATOMIC_RELAXED, __HIP_MEMORY_SCOPE_AGENT);
      __hip_atomic_store((u32*)(h_pp + (size_t)(par2 + 1) * HPP_Q + tix),
                         (u32)h0l | ((u32)h1l << 16),
                         __ATOMIC_RELAXED, __HIP_MEMORY_SCOPE_AGENT);
      if (is_last && s == nsteps - 1) {
        hs_out[b * 1024 + u0]     = h0;
        hs_out[b * 1024 + u0 + 1] = h1;
        cs_out[b * 1024 + u0]     = c0;
        cs_out[b * 1024 + u0 + 1] = c1;
      }
    }
    // phase D: grid barrier. All h data already at L3 (sc1); release store just
    // orders it (vmcnt drain). Polls RELAXED; NO acquire fences anywhere.
    __syncthreads();
    const int tag = tag0 + s + 1;
    if (tid == 0)
      __hip_atomic_store(slots + bid, tag, __ATOMIC_RELEASE, __HIP_MEMORY_SCOPE_AGENT);
    if (bid == 0) {
      if (w == 0) {
        for (;;) {
          int v0 = __hip_atomic_load(slots + lane,      __ATOMIC_RELAXED, __HIP_MEMORY_SCOPE_AGENT);
          int v1 = __hip_atomic_load(slots + 64 + lane, __ATOMIC_RELAXED, __HIP_MEMORY_SCOPE_AGENT);
          if (__all(v0 >= tag && v1 >= tag)) break;
          __builtin_amdgcn_s_sleep(1);
        }
        __builtin_amdgcn_fence(__ATOMIC_ACQ_REL, "agent");   // order polls before go fanout
        if (lane < 32)
          __hip_atomic_store(go_rep + lane * 16, tag, __ATOMIC_RELAXED, __HIP_MEMORY_SCOPE_AGENT);
      }
    } else if (tid == 0) {
      while (__hip_atomic_load(go_rep + (bid & 31) * 16, __ATOMIC_RELAXED, __HIP_MEMORY_SCOPE_AGENT) < tag)
        __builtin_amdgcn_s_sleep(2);
    }
    __syncthreads();   // also a compiler fence: next-step h loads can't hoist above
  }
  if (tid < 128) {
    c_glob[b * 1024 + u0]     = c0;
    c_glob[b * 1024 + u0 + 1] = c1;
  }
}

// ---------------- host launcher ----------------
extern "C" void kernel_launch(void* const* d_in, const int* in_sizes, int n_in,
                              void* d_out, int out_size, void* d_ws, size_t ws_size,
                              hipStream_t stream) {
  const float* x   = (const float*)d_in[0];
  const float* Wih = (const float*)d_in[1];
  const float* Whh = (const float*)d_in[2];
  const float* bih = (const float*)d_in[3];
  const float* bhh = (const float*)d_in[4];
  float* out = (float*)d_out;                         // FP32 output buffer

  float* outh = out;                                  // h_seq region = inter-layer fp32 acts
  const size_t OFF1 = (size_t)SEQ * BATCH * HID;      // 16777216
  const size_t OFF2 = OFF1 + (size_t)LAYERS * BATCH * HID;

  // workspace layout
  char* ws = (char*)d_ws;
  u16*   wih_hi = (u16*)ws;                                  // 8MB (per-layer)
  u16*   wih_lo = (u16*)(ws + (8ull  << 20));                // 8MB
  u16*   whh_hi = (u16*)(ws + (16ull << 20));                // 8MB
  u16*   whh_lo = (u16*)(ws + (24ull << 20));                // 8MB
  float* biasc  = (float*)(ws + (32ull << 20));              // 64KB (all layers)
  u16*   h_pp   = (u16*)(ws + (32ull << 20) + (64ull << 10));        // 256KB
  float* c_glob = (float*)(ws + (32ull << 20) + (320ull << 10));     // 128KB
  int*   bar    = (int*)(ws + (32ull << 20) + (448ull << 10));       // 4KB: slots[128] ++ go_rep[512]
  char*  dynws  = ws + (33ull << 20);

  // chunk T: 33MB + T*(64KB xh + 64KB xl + 512KB gates) <= ws_size
  int T = 128;
  while (T > 8 && (33ull << 20) + (size_t)T * (640ull << 10) > ws_size) T >>= 1;
  const int nchunk = SEQ / T;
  u16*   xb_hi = (u16*)dynws;                                          // T*32*1024
  u16*   xb_lo = (u16*)(dynws + (size_t)T * BATCH * HID * sizeof(u16));
  float* gates = (float*)(dynws + (size_t)2 * T * BATCH * HID * sizeof(u16));

  hipFuncSetAttribute(reinterpret_cast<const void*>(lstm_scan),
                      hipFuncAttributeMaxDynamicSharedMemorySize, SSMEM);

  hipMemsetAsync(bar, 0, 4096, stream);
  bias_comb_kernel<<<(LAYERS * G4 + 255) / 256, 256, 0, stream>>>(bih, bhh, biasc, LAYERS * G4);

  int tag0 = 0;
  for (int l = 0; l < LAYERS; ++l) {
    cvt_split_kernel<<<G4 * HID / 4 / 256, 256, 0, stream>>>(
        Wih + (size_t)l * G4 * HID, wih_hi, wih_lo, G4 * HID / 4);
    cvt_split_kernel<<<G4 * HID / 4 / 256, 256, 0, stream>>>(
        Whh + (size_t)l * G4 * HID, whh_hi, whh_lo, G4 * HID / 4);
    hipMemsetAsync(h_pp, 0, 4 * HPP_Q * sizeof(u16), stream);
    hipMemsetAsync(c_glob, 0, BATCH * HID * sizeof(float), stream);
    for (int cch = 0; cch < nchunk; ++cch) {
      const float* asrc = (l == 0) ? (x + (size_t)cch * T * BATCH * HID)
                                   : (outh + (size_t)cch * T * BATCH * HID);
      cvt_split_kernel<<<T * BATCH * HID / 4 / 256, 256, 0, stream>>>(
          asrc, xb_hi, xb_lo, T * BATCH * HID / 4);
      gemm_xproj<<<dim3(T * BATCH / 128, 32), 256, 0, stream>>>(
          xb_hi, xb_lo, wih_hi, wih_lo, biasc + l * G4, gates);
      lstm_scan<<<128, 256, SSMEM, stream>>>(
          gates, whh_hi, whh_lo, h_pp, c_glob,
          outh,
          out + OFF1 + (size_t)l * BATCH * HID,
          out + OFF2 + (size_t)l * BATCH * HID,
          bar, bar + 128,
          cch * T, tag0, T, (cch == nchunk - 1) ? 1 : 0);
      tag0 += T;
    }
  }
  (void)in_sizes; (void)n_in; (void)out_size;
}